// Round 6
// baseline (274.271 us; speedup 1.0000x reference)
//
#include <hip/hip_runtime.h>
#include <hip/hip_bf16.h>

// Corr: B=4, C=256, H=W=64, HW=4096, TOPK=3, rat_s=0.05 -> sigma=3.2, 2*sigma^2=20.48
// s[m,n] = alpha * (1 - exp(-(dr^2+dc^2)/20.48)) * <xn_m, xn_n>  (symmetric)
// xc[m,n] = exp(2 s[m,n]) / (sm[m] sm[n]),  sm[m] = sum_n exp(s[m,n])
// out[b,k,col] = top-3 over m of xc[m,col]
//
// R1: XCD<->batch binding + triangular-symmetric rowsum.
// R2: log-domain top-k + per-wave mask table.
// R3: non-atomic rowsum partials.
// R5: barrier-free GEMM — MFMA fragments loaded DIRECTLY global->VGPR (K=256,
//     fragments are 64B-coalesced per 16-row group; L2/XCD-resident). No LDS
//     staging, no __syncthreads in the K-loop (the R3/R4 dbuf still drained
//     vmcnt(0) at every barrier = the m97 plateau). Register double-buffer
//     over K. ins3 via v_med3_f32: 5 ops -> 3 ops exact.

#define HW 4096
#define CDIM 256
#define INV2S2 0.048828125f  // 1/20.48
#define NEGINF -1e30f

typedef __bf16 bf16;
typedef __attribute__((ext_vector_type(8))) __bf16 bf16x8;
typedef __attribute__((ext_vector_type(4))) float f32x4;

__device__ __forceinline__ void ins3(float v, float& t0, float& t1, float& t2) {
    // maintains t0>=t1>=t2; exact top-3 insert in 3 VALU ops
    float n0 = fmaxf(t0, v);
    float n1 = __builtin_amdgcn_fmed3f(t0, t1, v);
    float n2 = __builtin_amdgcn_fmed3f(t1, t2, v);
    t0 = n0; t1 = n1; t2 = n2;
}

// triangular decode: t = mt*(mt+1)/2 + nt, nt <= mt
__device__ __forceinline__ void decode_tri(int t, int& mt, int& nt) {
    int m = (int)((sqrtf(8.f * (float)t + 1.f) - 1.f) * 0.5f);
    while ((m + 1) * (m + 2) / 2 <= t) ++m;
    while (m * (m + 1) / 2 > t) --m;
    mt = m;
    nt = t - m * (m + 1) / 2;
}

// ---------------- normalize + transpose to bf16 xnT[b][pixel][channel] ----------------
__global__ __launch_bounds__(256) void corr_norm(const float* __restrict__ x,
                                                 bf16* __restrict__ xnT) {
    __shared__ float red[4][64];
    __shared__ float invn[64];
    int tid = threadIdx.x;
    int pl = tid & 63, cg = tid >> 6;       // pixel-lane, channel-group
    int P = blockIdx.x * 64 + pl;           // flat index over b*HW
    int b = P >> 12;
    int pix = P & 4095;
    const float* xb = x + ((size_t)(b * CDIM + cg * 64) << 12) + pix;
    float v[64];
    float ss = 0.f;
#pragma unroll
    for (int j = 0; j < 64; ++j) {
        v[j] = xb[(size_t)j << 12];
        ss += v[j] * v[j];
    }
    red[cg][pl] = ss;
    __syncthreads();
    if (tid < 64) {
        float s = red[0][tid] + red[1][tid] + red[2][tid] + red[3][tid];
        invn[tid] = 1.0f / fmaxf(sqrtf(s), 1e-12f);
    }
    __syncthreads();
    float inv = invn[pl];
    bf16* o = xnT + (size_t)P * CDIM + cg * 64;
#pragma unroll
    for (int j0 = 0; j0 < 64; j0 += 8) {
        bf16x8 pk;
#pragma unroll
        for (int j = 0; j < 8; ++j) pk[j] = (bf16)(v[j0 + j] * inv);
        *(bf16x8*)(o + j0) = pk;
    }
}

// ------------- GEMM tile core: 128x128, K=256, direct global->VGPR, no barriers -------------
// Fragment af[i]: row = mbase + wm*64 + i*16 + l15, k = k0 + quad*8 (16B).
// Quads with equal l15 cover 64 contiguous bytes of one row -> coalesced 64B segments.
__device__ __forceinline__ void gemm_tile(const bf16* __restrict__ xb, int mbase, int nbase,
                                          f32x4 (&acc)[4][4]) {
    const int tid = threadIdx.x;
    const int wave = tid >> 6, lane = tid & 63;
    const int wm = wave >> 1, wn = wave & 1;
    const int l15 = lane & 15, quad = lane >> 4;
    const bf16* ap[4];
    const bf16* bp[4];
#pragma unroll
    for (int i = 0; i < 4; ++i) {
        ap[i] = xb + ((size_t)(mbase + wm * 64 + i * 16 + l15) << 8) + quad * 8;
        bp[i] = xb + ((size_t)(nbase + wn * 64 + i * 16 + l15) << 8) + quad * 8;
    }
#pragma unroll
    for (int mi = 0; mi < 4; ++mi)
#pragma unroll
        for (int ni = 0; ni < 4; ++ni) acc[mi][ni] = (f32x4)0.f;

    bf16x8 afr[2][4], bfr[2][4];
#pragma unroll
    for (int i = 0; i < 4; ++i) {
        afr[0][i] = *(const bf16x8*)(ap[i]);
        bfr[0][i] = *(const bf16x8*)(bp[i]);
    }
#pragma unroll
    for (int kk = 0; kk < 8; ++kk) {
        const int cur = kk & 1, nxt = cur ^ 1;
        if (kk < 7) {
#pragma unroll
            for (int i = 0; i < 4; ++i) {
                afr[nxt][i] = *(const bf16x8*)(ap[i] + (kk + 1) * 32);
                bfr[nxt][i] = *(const bf16x8*)(bp[i] + (kk + 1) * 32);
            }
        }
#pragma unroll
        for (int mi = 0; mi < 4; ++mi)
#pragma unroll
            for (int ni = 0; ni < 4; ++ni)
                acc[mi][ni] = __builtin_amdgcn_mfma_f32_16x16x32_bf16(afr[cur][mi], bfr[cur][ni],
                                                                      acc[mi][ni], 0, 0, 0);
    }
}

// build per-wave extended mask table: extw[j] = scale*(1 - exp(-(adr^2+(j-63)^2)/20.48))
__device__ __forceinline__ void build_ext(float* extw, int lane, int adr, float scale) {
    float fr2 = (float)(adr * adr);
#pragma unroll
    for (int h = 0; h < 2; ++h) {
        int j = lane + h * 64;
        float d = (float)(j - 63);
        extw[j] = scale * (1.f - __expf(-(fr2 + d * d) * INV2S2));
    }
}

// ---------------- pass B: rowsum partials, triangular tiles, no atomics ----------------
// rpart[((b*32 + strip)*32 + slot)*128 + j]: strip s gets row-sums from tiles (s, nt<=s)
// at slot nt, and col-sums from tiles (mt>s, s) at slot mt. Every slot written once.
__global__ __launch_bounds__(256) void corr_rowsum(const bf16* __restrict__ xnT,
                                                   const float* __restrict__ alpha_p,
                                                   float* __restrict__ rpart) {
    __shared__ float ext[4][128];
    __shared__ float rbuf[2][128];
    __shared__ float cbuf[2][128];
    int tid = threadIdx.x;
    int lin = blockIdx.x;
    int xcd = lin & 7;
    int b = xcd >> 1;
    int t = ((lin >> 3) << 1) + (xcd & 1);  // [0, 528)
    int mt, nt;
    decode_tri(t, mt, nt);
    int mbase = mt * 128, nbase = nt * 128;
    int wave = tid >> 6, lane = tid & 63;
    int wm = wave >> 1, wn = wave & 1, l15 = lane & 15, quad = lane >> 4;
    int rowi = (mbase + wm * 64) >> 6;
    int coli = (nbase + wn * 64) >> 6;
    int adr = rowi - coli; if (adr < 0) adr = -adr;
    build_ext(ext[wave], lane, adr, alpha_p[0]);  // wave-private: no barrier needed

    f32x4 acc[4][4];
    gemm_tile(xnT + ((size_t)b << 20), mbase, nbase, acc);

    const float* extw = &ext[wave][15 + quad * 4 - l15];
    float colpart[4] = {0.f, 0.f, 0.f, 0.f};
#pragma unroll
    for (int mi = 0; mi < 4; ++mi) {
#pragma unroll
        for (int r = 0; r < 4; ++r) {
            float ssum = 0.f;
#pragma unroll
            for (int ni = 0; ni < 4; ++ni) {
                float s = extw[48 + (mi - ni) * 16 + r] * acc[mi][ni][r];
                float e = __expf(s);
                ssum += e;
                colpart[ni] += e;
            }
            ssum += __shfl_xor(ssum, 1);
            ssum += __shfl_xor(ssum, 2);
            ssum += __shfl_xor(ssum, 4);
            ssum += __shfl_xor(ssum, 8);
            if (l15 == 0) rbuf[wn][wm * 64 + mi * 16 + quad * 4 + r] = ssum;
        }
    }
#pragma unroll
    for (int ni = 0; ni < 4; ++ni) {
        float c = colpart[ni];
        c += __shfl_xor(c, 16);
        c += __shfl_xor(c, 32);
        if (quad == 0) cbuf[wm][wn * 64 + ni * 16 + l15] = c;
    }
    __syncthreads();
    if (tid < 128) {
        rpart[(size_t)((b * 32 + mt) * 32 + nt) * 128 + tid] = rbuf[0][tid] + rbuf[1][tid];
    } else if (mt != nt) {
        int j = tid - 128;
        rpart[(size_t)((b * 32 + nt) * 32 + mt) * 128 + j] = cbuf[0][j] + cbuf[1][j];
    }
}

// ---------------- slot-reduce + reciprocal + negative log ----------------
__global__ __launch_bounds__(256) void corr_recip(const float* __restrict__ rpart,
                                                  float* __restrict__ ism,
                                                  float* __restrict__ lsm) {
    int i = blockIdx.x * 256 + threadIdx.x;
    if (i >= 4 * HW) return;
    int b = i >> 12, gr = i & 4095, s = gr >> 7, j = gr & 127;
    const float* base = rpart + (size_t)((b * 32 + s) * 32) * 128 + j;
    float sum = 0.f;
#pragma unroll
    for (int sl = 0; sl < 32; ++sl) sum += base[sl * 128];
    ism[i] = 1.0f / sum;
    lsm[i] = -__logf(sum);
}

// ---------------- pass C: log-domain per-tile column top-3 (full grid, XCD-bound) ----------------
__global__ __launch_bounds__(256) void corr_topk(const bf16* __restrict__ xnT,
                                                 const float* __restrict__ alpha_p,
                                                 const float* __restrict__ lsm,
                                                 float* __restrict__ wtop) {
    __shared__ float ext[4][128];
    __shared__ float mbuf[2][128][3];
    int tid = threadIdx.x;
    int lin = blockIdx.x;
    int xcd = lin & 7;
    int b = xcd >> 1;
    int t = ((lin >> 3) << 1) + (xcd & 1);  // [0, 1024)
    int mtile = t >> 5, ntile = t & 31;
    int mbase = mtile * 128, nbase = ntile * 128;
    int wave = tid >> 6, lane = tid & 63;
    int wm = wave >> 1, wn = wave & 1, l15 = lane & 15, quad = lane >> 4;
    int rowi = (mbase + wm * 64) >> 6;
    int coli = (nbase + wn * 64) >> 6;
    int adr = rowi - coli; if (adr < 0) adr = -adr;
    build_ext(ext[wave], lane, adr, 2.0f * alpha_p[0]);

    f32x4 acc[4][4];
    gemm_tile(xnT + ((size_t)b << 20), mbase, nbase, acc);

    float lr[4][4];
#pragma unroll
    for (int mi = 0; mi < 4; ++mi)
#pragma unroll
        for (int r = 0; r < 4; ++r)
            lr[mi][r] = lsm[(b << 12) + mbase + wm * 64 + mi * 16 + quad * 4 + r];
    const float* extw = &ext[wave][15 + quad * 4 - l15];
#pragma unroll
    for (int ni = 0; ni < 4; ++ni) {
        float t0 = NEGINF, t1 = NEGINF, t2 = NEGINF;
#pragma unroll
        for (int mi = 0; mi < 4; ++mi) {
#pragma unroll
            for (int r = 0; r < 4; ++r) {
                float key = fmaf(extw[48 + (mi - ni) * 16 + r], acc[mi][ni][r], lr[mi][r]);
                ins3(key, t0, t1, t2);
            }
        }
#pragma unroll
        for (int d = 16; d <= 32; d <<= 1) {
            float s0 = __shfl_xor(t0, d);
            float s1 = __shfl_xor(t1, d);
            float s2 = __shfl_xor(t2, d);
            ins3(s0, t0, t1, t2);
            ins3(s1, t0, t1, t2);
            ins3(s2, t0, t1, t2);
        }
        if (quad == 0) {
            int cl = wn * 64 + ni * 16 + l15;
            mbuf[wm][cl][0] = t0;
            mbuf[wm][cl][1] = t1;
            mbuf[wm][cl][2] = t2;
        }
    }
    __syncthreads();
    if (tid < 128) {
        float t0 = mbuf[0][tid][0], t1 = mbuf[0][tid][1], t2 = mbuf[0][tid][2];
        ins3(mbuf[1][tid][0], t0, t1, t2);
        ins3(mbuf[1][tid][1], t0, t1, t2);
        ins3(mbuf[1][tid][2], t0, t1, t2);
        size_t o = (((size_t)(b * 32 + mtile) << 12) + nbase + tid) * 3;
        wtop[o] = t0;
        wtop[o + 1] = t1;
        wtop[o + 2] = t2;
    }
}

// ---------------- final merge of 32 m-tile key-partials; exp + column scale ----------------
__global__ __launch_bounds__(256) void corr_merge(const float* __restrict__ wtop,
                                                  const float* __restrict__ ism,
                                                  float* __restrict__ out) {
    int idx = blockIdx.x * 256 + threadIdx.x;
    if (idx >= 4 * HW) return;
    int b = idx >> 12, col = idx & 4095;
    float t0 = NEGINF, t1 = NEGINF, t2 = NEGINF;
    for (int mt = 0; mt < 32; ++mt) {
        const float* q = wtop + (((size_t)(b * 32 + mt) << 12) + col) * 3;
        ins3(q[0], t0, t1, t2);
        ins3(q[1], t0, t1, t2);
        ins3(q[2], t0, t1, t2);
    }
    float ismc = ism[idx];
    out[((b * 3 + 0) << 12) + col] = __expf(t0) * ismc;
    out[((b * 3 + 1) << 12) + col] = __expf(t1) * ismc;
    out[((b * 3 + 2) << 12) + col] = __expf(t2) * ismc;
}

extern "C" void kernel_launch(void* const* d_in, const int* in_sizes, int n_in,
                              void* d_out, int out_size, void* d_ws, size_t ws_size,
                              hipStream_t stream) {
    const float* x = (const float*)d_in[0];
    const float* alpha = (const float*)d_in[1];
    float* out = (float*)d_out;
    char* ws = (char*)d_ws;
    bf16* xnT = (bf16*)ws;                                    // 8 MB
    float* ism = (float*)(ws + (8u << 20));                   // 64 KB
    float* lsm = (float*)(ws + (8u << 20) + (64u << 10));     // 64 KB
    // rpart (2 MB) and wtop (6 MB) share the same region: disjoint lifetimes
    // (rpart: rowsum->recip; wtop: topk->merge).
    float* rpart = (float*)(ws + (8u << 20) + (128u << 10));
    float* wtop  = (float*)(ws + (8u << 20) + (128u << 10));

    corr_norm<<<256, 256, 0, stream>>>(x, xnT);
    corr_rowsum<<<528 * 4, 256, 0, stream>>>(xnT, alpha, rpart);
    corr_recip<<<64, 256, 0, stream>>>(rpart, ism, lsm);
    corr_topk<<<1024 * 4, 256, 0, stream>>>(xnT, alpha, lsm, wtop);
    corr_merge<<<64, 256, 0, stream>>>(wtop, ism, out);
}

// Round 7
// 164.464 us; speedup vs baseline: 1.6677x; 1.6677x over previous
//
#include <hip/hip_runtime.h>
#include <hip/hip_bf16.h>

// Corr: B=4, C=256, H=W=64, HW=4096, TOPK=3, rat_s=0.05 -> sigma=3.2, 2*sigma^2=20.48
// s[m,n] = alpha * (1 - exp(-(dr^2+dc^2)/20.48)) * <xn_m, xn_n>  (symmetric)
// xc[m,n] = exp(2 s[m,n]) / (sm[m] sm[n]),  sm[m] = sum_n exp(s[m,n])
// out[b,k,col] = top-3 over m of xc[m,col]
//
// R1: XCD<->batch binding + triangular-symmetric rowsum.
// R2: log-domain top-k + per-wave mask table.
// R3: non-atomic partials + dbuf K-loop.  R4: k-slot swizzle (0 conflicts).
// R5 (reverted): direct global->VGPR fragments doubled L2 traffic, 4x segments.
// R6: TRIANGULAR topk — xc symmetric, so tile (mt>=nt) feeds BOTH strip nt
//     (column-dir, slot mt) and strip mt (row-dir via xc[c,n]=xc[n,c], slot nt).
//     528 tiles instead of 1024. Diagonal skips row-dir (duplicate+collision).

#define HW 4096
#define CDIM 256
#define INV2S2 0.048828125f  // 1/20.48
#define NEGINF -1e30f

typedef __bf16 bf16;
typedef __attribute__((ext_vector_type(8))) __bf16 bf16x8;
typedef __attribute__((ext_vector_type(4))) float f32x4;

#define GAS __attribute__((address_space(1)))
#define LAS __attribute__((address_space(3)))

__device__ __forceinline__ void ins3(float v, float& t0, float& t1, float& t2) {
    // maintains t0>=t1>=t2; exact top-3 insert in 3 VALU ops (v_max + 2x v_med3)
    float n0 = fmaxf(t0, v);
    float n1 = __builtin_amdgcn_fmed3f(t0, t1, v);
    float n2 = __builtin_amdgcn_fmed3f(t1, t2, v);
    t0 = n0; t1 = n1; t2 = n2;
}

// triangular decode: t = mt*(mt+1)/2 + nt, nt <= mt
__device__ __forceinline__ void decode_tri(int t, int& mt, int& nt) {
    int m = (int)((sqrtf(8.f * (float)t + 1.f) - 1.f) * 0.5f);
    while ((m + 1) * (m + 2) / 2 <= t) ++m;
    while (m * (m + 1) / 2 > t) --m;
    mt = m;
    nt = t - m * (m + 1) / 2;
}

// ---------------- normalize + transpose to bf16 xnT[b][pixel][channel] ----------------
__global__ __launch_bounds__(256) void corr_norm(const float* __restrict__ x,
                                                 bf16* __restrict__ xnT) {
    __shared__ float red[4][64];
    __shared__ float invn[64];
    int tid = threadIdx.x;
    int pl = tid & 63, cg = tid >> 6;
    int P = blockIdx.x * 64 + pl;
    int b = P >> 12;
    int pix = P & 4095;
    const float* xb = x + ((size_t)(b * CDIM + cg * 64) << 12) + pix;
    float v[64];
    float ss = 0.f;
#pragma unroll
    for (int j = 0; j < 64; ++j) {
        v[j] = xb[(size_t)j << 12];
        ss += v[j] * v[j];
    }
    red[cg][pl] = ss;
    __syncthreads();
    if (tid < 64) {
        float s = red[0][tid] + red[1][tid] + red[2][tid] + red[3][tid];
        invn[tid] = 1.0f / fmaxf(sqrtf(s), 1e-12f);
    }
    __syncthreads();
    float inv = invn[pl];
    bf16* o = xnT + (size_t)P * CDIM + cg * 64;
#pragma unroll
    for (int j0 = 0; j0 < 64; j0 += 8) {
        bf16x8 pk;
#pragma unroll
        for (int j = 0; j < 8; ++j) pk[j] = (bf16)(v[j0 + j] * inv);
        *(bf16x8*)(o + j0) = pk;
    }
}

// ---------------- GEMM tile core: 128x128, K=256, dbuf single-barrier, k-slot swizzle ----
__device__ __forceinline__ void gemm_tile(const bf16* __restrict__ xb, int mbase, int nbase,
                                          bf16* As, bf16* Bs, f32x4 (&acc)[4][4]) {
    const int tid = threadIdx.x;
    const int wave = tid >> 6;
    const int lane = tid & 63;
    const int wm = wave >> 1, wn = wave & 1;
    const int l15 = lane & 15, quad = lane >> 4;
#pragma unroll
    for (int mi = 0; mi < 4; ++mi)
#pragma unroll
        for (int ni = 0; ni < 4; ++ni) acc[mi][ni] = (f32x4)0.f;

    auto issue = [&](int kk, int buf) {
#pragma unroll
        for (int r = 0; r < 2; ++r) {
            int idx = r * 256 + tid;
            int prow = idx >> 2;
            int sub = ((idx & 3) - (prow >> 1)) & 3;  // swizzled k-group
            const bf16* gA = xb + ((size_t)(mbase + prow) << 8) + kk * 32 + (sub << 3);
            const bf16* gB = xb + ((size_t)(nbase + prow) << 8) + kk * 32 + (sub << 3);
            bf16* lA = As + buf * 4096 + ((r * 4 + wave) << 9);
            bf16* lB = Bs + buf * 4096 + ((r * 4 + wave) << 9);
            __builtin_amdgcn_global_load_lds((const GAS void*)gA, (LAS void*)lA, 16, 0, 0);
            __builtin_amdgcn_global_load_lds((const GAS void*)gB, (LAS void*)lB, 16, 0, 0);
        }
    };
    issue(0, 0);
    const int rslot = ((quad + (l15 >> 1)) & 3) * 8;
#pragma unroll
    for (int kk = 0; kk < 8; ++kk) {
        __syncthreads();
        if (kk < 7) issue(kk + 1, (kk + 1) & 1);
        int buf = kk & 1;
        bf16x8 af[4], bfr[4];
#pragma unroll
        for (int i = 0; i < 4; ++i) {
            af[i]  = *(const bf16x8*)(As + buf * 4096 + (wm * 64 + i * 16 + l15) * 32 + rslot);
            bfr[i] = *(const bf16x8*)(Bs + buf * 4096 + (wn * 64 + i * 16 + l15) * 32 + rslot);
        }
#pragma unroll
        for (int mi = 0; mi < 4; ++mi)
#pragma unroll
            for (int ni = 0; ni < 4; ++ni)
                acc[mi][ni] = __builtin_amdgcn_mfma_f32_16x16x32_bf16(af[mi], bfr[ni],
                                                                      acc[mi][ni], 0, 0, 0);
    }
}

// extw[j] = scale*(1 - exp(-(adr^2+(j-63)^2)/20.48)), j in [0,128) — wave-private
__device__ __forceinline__ void build_ext(float* extw, int lane, int adr, float scale) {
    float fr2 = (float)(adr * adr);
#pragma unroll
    for (int h = 0; h < 2; ++h) {
        int j = lane + h * 64;
        float d = (float)(j - 63);
        extw[j] = scale * (1.f - __expf(-(fr2 + d * d) * INV2S2));
    }
}

// ---------------- pass B: rowsum partials, triangular tiles, no atomics ----------------
__global__ __launch_bounds__(256) void corr_rowsum(const bf16* __restrict__ xnT,
                                                   const float* __restrict__ alpha_p,
                                                   float* __restrict__ rpart) {
    __shared__ __align__(16) bf16 SH[16384];  // As[2][4096] | Bs[2][4096]
    bf16* As = SH;
    bf16* Bs = SH + 8192;
    int tid = threadIdx.x;
    int lin = blockIdx.x;
    int xcd = lin & 7;
    int b = xcd >> 1;
    int t = ((lin >> 3) << 1) + (xcd & 1);  // [0, 528)
    int mt, nt;
    decode_tri(t, mt, nt);
    int mbase = mt * 128, nbase = nt * 128;
    int wave = tid >> 6, lane = tid & 63;
    int wm = wave >> 1, wn = wave & 1, l15 = lane & 15, quad = lane >> 4;
    int rowi = (mbase + wm * 64) >> 6;
    int coli = (nbase + wn * 64) >> 6;
    int adr = rowi - coli; if (adr < 0) adr = -adr;
    float alpha = alpha_p[0];

    f32x4 acc[4][4];
    gemm_tile(xnT + ((size_t)b << 20), mbase, nbase, As, Bs, acc);

    // epilogue scratch in dead buf0 of As (first 4KB)
    float* ext  = (float*)As;              // [4][128]
    float* rbuf = (float*)As + 512;        // [2][128]
    float* cbuf = (float*)As + 768;        // [2][128]
    build_ext(ext + wave * 128, lane, adr, alpha);

    const float* extw = ext + wave * 128 + 15 + quad * 4 - l15;
    float colpart[4] = {0.f, 0.f, 0.f, 0.f};
#pragma unroll
    for (int mi = 0; mi < 4; ++mi) {
#pragma unroll
        for (int r = 0; r < 4; ++r) {
            float ssum = 0.f;
#pragma unroll
            for (int ni = 0; ni < 4; ++ni) {
                float s = extw[48 + (mi - ni) * 16 + r] * acc[mi][ni][r];
                float e = __expf(s);
                ssum += e;
                colpart[ni] += e;
            }
            ssum += __shfl_xor(ssum, 1);
            ssum += __shfl_xor(ssum, 2);
            ssum += __shfl_xor(ssum, 4);
            ssum += __shfl_xor(ssum, 8);
            if (l15 == 0) rbuf[wn * 128 + wm * 64 + mi * 16 + quad * 4 + r] = ssum;
        }
    }
#pragma unroll
    for (int ni = 0; ni < 4; ++ni) {
        float c = colpart[ni];
        c += __shfl_xor(c, 16);
        c += __shfl_xor(c, 32);
        if (quad == 0) cbuf[wm * 128 + wn * 64 + ni * 16 + l15] = c;
    }
    __syncthreads();
    if (tid < 128) {
        rpart[(size_t)((b * 32 + mt) * 32 + nt) * 128 + tid] = rbuf[tid] + rbuf[128 + tid];
    } else if (mt != nt) {
        int j = tid - 128;
        rpart[(size_t)((b * 32 + nt) * 32 + mt) * 128 + j] = cbuf[j] + cbuf[128 + j];
    }
}

// ---------------- slot-reduce + reciprocal + negative log ----------------
__global__ __launch_bounds__(256) void corr_recip(const float* __restrict__ rpart,
                                                  float* __restrict__ ism,
                                                  float* __restrict__ lsm) {
    int i = blockIdx.x * 256 + threadIdx.x;
    if (i >= 4 * HW) return;
    int b = i >> 12, gr = i & 4095, s = gr >> 7, j = gr & 127;
    const float* base = rpart + (size_t)((b * 32 + s) * 32) * 128 + j;
    float sum = 0.f;
#pragma unroll
    for (int sl = 0; sl < 32; ++sl) sum += base[sl * 128];
    ism[i] = 1.0f / sum;
    lsm[i] = -__logf(sum);
}

// ---------------- pass C: triangular log-domain top-3, dual direction ----------------
// wtop[((b*32+strip)*32+slot)*128+j][3]: strip s slot j: j>=s from col-dir of tile
// (j,s); j<s from row-dir of tile (s,j). Every slot written exactly once.
__global__ __launch_bounds__(256) void corr_topk(const bf16* __restrict__ xnT,
                                                 const float* __restrict__ alpha_p,
                                                 const float* __restrict__ lsm,
                                                 float* __restrict__ wtop) {
    __shared__ __align__(16) bf16 SH[16384];  // 32KB: GEMM then epilogue scratch
    bf16* As = SH;
    bf16* Bs = SH + 8192;
    int tid = threadIdx.x;
    int lin = blockIdx.x;
    int xcd = lin & 7;
    int b = xcd >> 1;
    int t = ((lin >> 3) << 1) + (xcd & 1);  // [0, 528)
    int mt, nt;
    decode_tri(t, mt, nt);
    int mbase = mt * 128, nbase = nt * 128;
    int wave = tid >> 6, lane = tid & 63;
    int wm = wave >> 1, wn = wave & 1, l15 = lane & 15, quad = lane >> 4;
    int rowi = (mbase + wm * 64) >> 6;
    int coli = (nbase + wn * 64) >> 6;
    int adr = rowi - coli; if (adr < 0) adr = -adr;
    float a2 = 2.0f * alpha_p[0];

    f32x4 acc[4][4];
    gemm_tile(xnT + ((size_t)b << 20), mbase, nbase, As, Bs, acc);
    __syncthreads();  // all GEMM LDS dead; whole 32KB reusable

    float* F = (float*)SH;
    float* ext  = F;            // [4][128]   (2KB)
    float* mbuf = F + 512;      // [2][128][3] (3KB)
    float* rtop = F + 2048;     // [128][9][4] f32x4, 9-pad breaks bank aliasing (18KB)
    build_ext(ext + wave * 128, lane, adr, a2);  // wave-private

    float lr[4][4];
#pragma unroll
    for (int mi = 0; mi < 4; ++mi)
#pragma unroll
        for (int r = 0; r < 4; ++r)
            lr[mi][r] = lsm[(b << 12) + mbase + wm * 64 + mi * 16 + quad * 4 + r];
    float lc[4];
#pragma unroll
    for (int ni = 0; ni < 4; ++ni)
        lc[ni] = lsm[(b << 12) + nbase + wn * 64 + ni * 16 + l15];

    const float* extw = ext + wave * 128 + 15 + quad * 4 - l15;

    // ---- column direction: top3 over rows for each tile column ----
#pragma unroll
    for (int ni = 0; ni < 4; ++ni) {
        float t0 = NEGINF, t1 = NEGINF, t2 = NEGINF;
#pragma unroll
        for (int mi = 0; mi < 4; ++mi) {
#pragma unroll
            for (int r = 0; r < 4; ++r) {
                float key = fmaf(extw[48 + (mi - ni) * 16 + r], acc[mi][ni][r], lr[mi][r]);
                ins3(key, t0, t1, t2);
            }
        }
#pragma unroll
        for (int d = 16; d <= 32; d <<= 1) {
            float s0 = __shfl_xor(t0, d);
            float s1 = __shfl_xor(t1, d);
            float s2 = __shfl_xor(t2, d);
            ins3(s0, t0, t1, t2);
            ins3(s1, t0, t1, t2);
            ins3(s2, t0, t1, t2);
        }
        if (quad == 0) {
            int cl = wn * 64 + ni * 16 + l15;
            mbuf[(wm * 128 + cl) * 3 + 0] = t0;
            mbuf[(wm * 128 + cl) * 3 + 1] = t1;
            mbuf[(wm * 128 + cl) * 3 + 2] = t2;
        }
    }

    // ---- row direction (xc[c,n]=xc[n,c]): top3 over cols for each tile row ----
    if (mt != nt) {
#pragma unroll
        for (int mi = 0; mi < 4; ++mi) {
#pragma unroll
            for (int r = 0; r < 4; ++r) {
                float u0 = NEGINF, u1 = NEGINF, u2 = NEGINF;
#pragma unroll
                for (int ni = 0; ni < 4; ++ni) {
                    float key = fmaf(extw[48 + (mi - ni) * 16 + r], acc[mi][ni][r], lc[ni]);
                    ins3(key, u0, u1, u2);
                }
#pragma unroll
                for (int d = 4; d <= 8; d <<= 1) {
                    float s0 = __shfl_xor(u0, d);
                    float s1 = __shfl_xor(u1, d);
                    float s2 = __shfl_xor(u2, d);
                    ins3(s0, u0, u1, u2);
                    ins3(s1, u0, u1, u2);
                    ins3(s2, u0, u1, u2);
                }
                if (l15 < 4) {
                    int row = wm * 64 + mi * 16 + quad * 4 + r;
                    int slot = wn * 4 + l15;
                    *(f32x4*)(rtop + (row * 9 + slot) * 4) = (f32x4){u0, u1, u2, 0.f};
                }
            }
        }
    }
    __syncthreads();
    if (tid < 128) {
        // column-direction merge: strip nt, slot mt, column nbase+tid
        float t0 = mbuf[tid * 3], t1 = mbuf[tid * 3 + 1], t2 = mbuf[tid * 3 + 2];
        ins3(mbuf[(128 + tid) * 3 + 0], t0, t1, t2);
        ins3(mbuf[(128 + tid) * 3 + 1], t0, t1, t2);
        ins3(mbuf[(128 + tid) * 3 + 2], t0, t1, t2);
        size_t o = ((size_t)((b * 32 + nt) * 32 + mt) * 128 + tid) * 3;
        wtop[o] = t0;
        wtop[o + 1] = t1;
        wtop[o + 2] = t2;
        if (mt != nt) {
            // row-direction merge: strip mt, slot nt, column mbase+tid
            float v0 = NEGINF, v1 = NEGINF, v2 = NEGINF;
#pragma unroll
            for (int sl = 0; sl < 8; ++sl) {
                f32x4 q = *(const f32x4*)(rtop + (tid * 9 + sl) * 4);
                ins3(q[0], v0, v1, v2);
                ins3(q[1], v0, v1, v2);
                ins3(q[2], v0, v1, v2);
            }
            size_t o2 = ((size_t)((b * 32 + mt) * 32 + nt) * 128 + tid) * 3;
            wtop[o2] = v0;
            wtop[o2 + 1] = v1;
            wtop[o2 + 2] = v2;
        }
    }
}

// ---------------- final merge of 32 slot-partials per column; exp + column scale ----------------
__global__ __launch_bounds__(256) void corr_merge(const float* __restrict__ wtop,
                                                  const float* __restrict__ ism,
                                                  float* __restrict__ out) {
    int idx = blockIdx.x * 256 + threadIdx.x;
    if (idx >= 4 * HW) return;
    int b = idx >> 12, col = idx & 4095;
    int strip = col >> 7, j = col & 127;
    const float* base = wtop + ((size_t)((b * 32 + strip) * 32) * 128 + j) * 3;
    float t0 = NEGINF, t1 = NEGINF, t2 = NEGINF;
    for (int sl = 0; sl < 32; ++sl) {
        const float* q = base + (size_t)sl * 128 * 3;
        ins3(q[0], t0, t1, t2);
        ins3(q[1], t0, t1, t2);
        ins3(q[2], t0, t1, t2);
    }
    float ismc = ism[idx];
    out[((b * 3 + 0) << 12) + col] = __expf(t0) * ismc;
    out[((b * 3 + 1) << 12) + col] = __expf(t1) * ismc;
    out[((b * 3 + 2) << 12) + col] = __expf(t2) * ismc;
}

extern "C" void kernel_launch(void* const* d_in, const int* in_sizes, int n_in,
                              void* d_out, int out_size, void* d_ws, size_t ws_size,
                              hipStream_t stream) {
    const float* x = (const float*)d_in[0];
    const float* alpha = (const float*)d_in[1];
    float* out = (float*)d_out;
    char* ws = (char*)d_ws;
    bf16* xnT = (bf16*)ws;                                    // 8 MB
    float* ism = (float*)(ws + (8u << 20));                   // 64 KB
    float* lsm = (float*)(ws + (8u << 20) + (64u << 10));     // 64 KB
    float* rpart = (float*)(ws + (8u << 20) + (128u << 10));  // 2 MB (rowsum->recip)
    float* wtop  = (float*)(ws + (8u << 20) + (128u << 10));  // 6 MB (topk->merge)

    corr_norm<<<256, 256, 0, stream>>>(x, xnT);
    corr_rowsum<<<528 * 4, 256, 0, stream>>>(xnT, alpha, rpart);
    corr_recip<<<64, 256, 0, stream>>>(rpart, ism, lsm);
    corr_topk<<<528 * 4, 256, 0, stream>>>(xnT, alpha, lsm, wtop);
    corr_merge<<<64, 256, 0, stream>>>(wtop, ism, out);
}

// Round 9
// 156.085 us; speedup vs baseline: 1.7572x; 1.0537x over previous
//
#include <hip/hip_runtime.h>
#include <hip/hip_bf16.h>

// Corr: B=4, C=256, H=W=64, HW=4096, TOPK=3, rat_s=0.05 -> sigma=3.2, 2*sigma^2=20.48
// s[m,n] = alpha * (1 - exp(-(dr^2+dc^2)/20.48)) * <xn_m, xn_n>  (symmetric)
// xc[m,n] = exp(2 s[m,n]) / (sm[m] sm[n]),  sm[m] = sum_n exp(s[m,n])
// out[b,k,col] = top-3 over m of xc[m,col]
//
// R1: XCD<->batch binding. R2: log-domain top-k. R3: non-atomic partials.
// R4: k-slot swizzle (0 bank conflicts). R6: triangular dual-direction topk.
// R7 (REVERTED): raw-asm vmcnt(4) never-drain barriers with global_load_lds
//     broke numerics (absmax 7e-8) -- LDS-DMA completion is only safely ordered
//     by full __syncthreads on gfx950. Keep the exact parts: e[7][4] register
//     mask table + 1-stage row-dir shuffle.
// R8: proven R6 2-buffer __syncthreads K-loop restored; rtop relaid (stride 48,
//     base F+1280) to fix R6's latent 512B LDS overflow.

#define HW 4096
#define CDIM 256
#define INV2S2 0.048828125f  // 1/20.48
#define NEGINF -1e30f

typedef __bf16 bf16;
typedef __attribute__((ext_vector_type(8))) __bf16 bf16x8;
typedef __attribute__((ext_vector_type(4))) float f32x4;

#define GAS __attribute__((address_space(1)))
#define LAS __attribute__((address_space(3)))

__device__ __forceinline__ void ins3(float v, float& t0, float& t1, float& t2) {
    // maintains t0>=t1>=t2; exact top-3 insert in 3 VALU ops (v_max + 2x v_med3)
    float n0 = fmaxf(t0, v);
    float n1 = __builtin_amdgcn_fmed3f(t0, t1, v);
    float n2 = __builtin_amdgcn_fmed3f(t1, t2, v);
    t0 = n0; t1 = n1; t2 = n2;
}

// triangular decode: t = mt*(mt+1)/2 + nt, nt <= mt
__device__ __forceinline__ void decode_tri(int t, int& mt, int& nt) {
    int m = (int)((sqrtf(8.f * (float)t + 1.f) - 1.f) * 0.5f);
    while ((m + 1) * (m + 2) / 2 <= t) ++m;
    while (m * (m + 1) / 2 > t) --m;
    mt = m;
    nt = t - m * (m + 1) / 2;
}

// ---------------- normalize + transpose to bf16 xnT[b][pixel][channel] ----------------
__global__ __launch_bounds__(256) void corr_norm(const float* __restrict__ x,
                                                 bf16* __restrict__ xnT) {
    __shared__ float red[4][64];
    __shared__ float invn[64];
    int tid = threadIdx.x;
    int pl = tid & 63, cg = tid >> 6;
    int P = blockIdx.x * 64 + pl;
    int b = P >> 12;
    int pix = P & 4095;
    const float* xb = x + ((size_t)(b * CDIM + cg * 64) << 12) + pix;
    float v[64];
    float ss = 0.f;
#pragma unroll
    for (int j = 0; j < 64; ++j) {
        v[j] = xb[(size_t)j << 12];
        ss += v[j] * v[j];
    }
    red[cg][pl] = ss;
    __syncthreads();
    if (tid < 64) {
        float s = red[0][tid] + red[1][tid] + red[2][tid] + red[3][tid];
        invn[tid] = 1.0f / fmaxf(sqrtf(s), 1e-12f);
    }
    __syncthreads();
    float inv = invn[pl];
    bf16* o = xnT + (size_t)P * CDIM + cg * 64;
#pragma unroll
    for (int j0 = 0; j0 < 64; j0 += 8) {
        bf16x8 pk;
#pragma unroll
        for (int j = 0; j < 8; ++j) pk[j] = (bf16)(v[j0 + j] * inv);
        *(bf16x8*)(o + j0) = pk;
    }
}

// ---------------- GEMM tile core: 128x128, K=256, dbuf single-barrier, k-slot swizzle ----
// (R6-proven structure: __syncthreads per k-step; prefetch issued right after it.)
__device__ __forceinline__ void gemm_tile(const bf16* __restrict__ xb, int mbase, int nbase,
                                          bf16* As, bf16* Bs, f32x4 (&acc)[4][4]) {
    const int tid = threadIdx.x;
    const int wave = tid >> 6;
    const int lane = tid & 63;
    const int wm = wave >> 1, wn = wave & 1;
    const int l15 = lane & 15, quad = lane >> 4;
#pragma unroll
    for (int mi = 0; mi < 4; ++mi)
#pragma unroll
        for (int ni = 0; ni < 4; ++ni) acc[mi][ni] = (f32x4)0.f;

    auto issue = [&](int kk, int buf) {
#pragma unroll
        for (int r = 0; r < 2; ++r) {
            int idx = r * 256 + tid;
            int prow = idx >> 2;
            int sub = ((idx & 3) - (prow >> 1)) & 3;  // swizzled k-group
            const bf16* gA = xb + ((size_t)(mbase + prow) << 8) + kk * 32 + (sub << 3);
            const bf16* gB = xb + ((size_t)(nbase + prow) << 8) + kk * 32 + (sub << 3);
            bf16* lA = As + buf * 4096 + ((r * 4 + wave) << 9);
            bf16* lB = Bs + buf * 4096 + ((r * 4 + wave) << 9);
            __builtin_amdgcn_global_load_lds((const GAS void*)gA, (LAS void*)lA, 16, 0, 0);
            __builtin_amdgcn_global_load_lds((const GAS void*)gB, (LAS void*)lB, 16, 0, 0);
        }
    };
    issue(0, 0);
    const int rslot = ((quad + (l15 >> 1)) & 3) * 8;
#pragma unroll
    for (int kk = 0; kk < 8; ++kk) {
        __syncthreads();
        if (kk < 7) issue(kk + 1, (kk + 1) & 1);
        int buf = kk & 1;
        bf16x8 af[4], bfr[4];
#pragma unroll
        for (int i = 0; i < 4; ++i) {
            af[i]  = *(const bf16x8*)(As + buf * 4096 + (wm * 64 + i * 16 + l15) * 32 + rslot);
            bfr[i] = *(const bf16x8*)(Bs + buf * 4096 + (wn * 64 + i * 16 + l15) * 32 + rslot);
        }
#pragma unroll
        for (int mi = 0; mi < 4; ++mi)
#pragma unroll
            for (int ni = 0; ni < 4; ++ni)
                acc[mi][ni] = __builtin_amdgcn_mfma_f32_16x16x32_bf16(af[mi], bfr[ni],
                                                                      acc[mi][ni], 0, 0, 0);
    }
    // post-loop: all waves past the kk=7 barrier; iter-7 reads hit buf1 only,
    // so As/Bs buf0 regions are dead and reusable as epilogue scratch.
}

// extw[j] = scale*(1 - exp(-(adr^2+(j-63)^2)/20.48)), j in [0,128) — wave-private
__device__ __forceinline__ void build_ext(float* extw, int lane, int adr, float scale) {
    float fr2 = (float)(adr * adr);
#pragma unroll
    for (int h = 0; h < 2; ++h) {
        int j = lane + h * 64;
        float d = (float)(j - 63);
        extw[j] = scale * (1.f - __expf(-(fr2 + d * d) * INV2S2));
    }
}

// per-lane register table e[dm][r], dm = mi-ni+3; exact same values as the
// former per-key LDS reads (28 ds_read once instead of ~190 per wave).
__device__ __forceinline__ void load_etab(const float* extw_wave, int quad, int l15,
                                          float (&e)[7][4]) {
    const float* p = extw_wave + 63 + quad * 4 - l15;
#pragma unroll
    for (int dm = 0; dm < 7; ++dm)
#pragma unroll
        for (int r = 0; r < 4; ++r) e[dm][r] = p[(dm - 3) * 16 + r];
}

// ---------------- pass B: rowsum partials, triangular tiles, no atomics ----------------
// rpart[((b*32 + strip)*32 + slot)*128 + j]: strip s gets row-sums from tiles (s, nt<=s)
// at slot nt, and col-sums from tiles (mt>s, s) at slot mt. Every slot written once.
__global__ __launch_bounds__(256) void corr_rowsum(const bf16* __restrict__ xnT,
                                                   const float* __restrict__ alpha_p,
                                                   float* __restrict__ rpart) {
    __shared__ __align__(16) bf16 SH[16384];  // 32KB: As[2][4096] | Bs[2][4096]
    bf16* As = SH;
    bf16* Bs = SH + 8192;
    int tid = threadIdx.x;
    int lin = blockIdx.x;
    int xcd = lin & 7;
    int b = xcd >> 1;
    int t = ((lin >> 3) << 1) + (xcd & 1);  // [0, 528)
    int mt, nt;
    decode_tri(t, mt, nt);
    int mbase = mt * 128, nbase = nt * 128;
    int wave = tid >> 6, lane = tid & 63;
    int wm = wave >> 1, wn = wave & 1, l15 = lane & 15, quad = lane >> 4;
    int rowi = (mbase + wm * 64) >> 6;
    int coli = (nbase + wn * 64) >> 6;
    int adr = rowi - coli; if (adr < 0) adr = -adr;
    float alpha = alpha_p[0];

    f32x4 acc[4][4];
    gemm_tile(xnT + ((size_t)b << 20), mbase, nbase, As, Bs, acc);

    // epilogue scratch in dead As-buf0 (bytes 0..4095)
    float* F = (float*)SH;
    float* ext  = F;              // [4][128] wave-private
    float* rbuf = F + 512;        // [2][128]
    float* cbuf = F + 768;        // [2][128]
    build_ext(ext + wave * 128, lane, adr, alpha);
    float e[7][4];
    load_etab(ext + wave * 128, quad, l15, e);

    float colpart[4] = {0.f, 0.f, 0.f, 0.f};
#pragma unroll
    for (int mi = 0; mi < 4; ++mi) {
#pragma unroll
        for (int r = 0; r < 4; ++r) {
            float ssum = 0.f;
#pragma unroll
            for (int ni = 0; ni < 4; ++ni) {
                float s = e[mi - ni + 3][r] * acc[mi][ni][r];
                float ev = __expf(s);
                ssum += ev;
                colpart[ni] += ev;
            }
            ssum += __shfl_xor(ssum, 1);
            ssum += __shfl_xor(ssum, 2);
            ssum += __shfl_xor(ssum, 4);
            ssum += __shfl_xor(ssum, 8);
            if (l15 == 0) rbuf[wn * 128 + wm * 64 + mi * 16 + quad * 4 + r] = ssum;
        }
    }
#pragma unroll
    for (int ni = 0; ni < 4; ++ni) {
        float c = colpart[ni];
        c += __shfl_xor(c, 16);
        c += __shfl_xor(c, 32);
        if (quad == 0) cbuf[wm * 128 + wn * 64 + ni * 16 + l15] = c;
    }
    __syncthreads();
    if (tid < 128) {
        rpart[(size_t)((b * 32 + mt) * 32 + nt) * 128 + tid] = rbuf[tid] + rbuf[128 + tid];
    } else if (mt != nt) {
        int j = tid - 128;
        rpart[(size_t)((b * 32 + nt) * 32 + mt) * 128 + j] = cbuf[j] + cbuf[128 + j];
    }
}

// ---------------- slot-reduce + reciprocal + negative log ----------------
__global__ __launch_bounds__(256) void corr_recip(const float* __restrict__ rpart,
                                                  float* __restrict__ ism,
                                                  float* __restrict__ lsm) {
    int i = blockIdx.x * 256 + threadIdx.x;
    if (i >= 4 * HW) return;
    int b = i >> 12, gr = i & 4095, s = gr >> 7, j = gr & 127;
    const float* base = rpart + (size_t)((b * 32 + s) * 32) * 128 + j;
    float sum = 0.f;
#pragma unroll
    for (int sl = 0; sl < 32; ++sl) sum += base[sl * 128];
    ism[i] = 1.0f / sum;
    lsm[i] = -__logf(sum);
}

// ---------------- pass C: triangular log-domain top-3, dual direction ----------------
// wtop[((b*32+strip)*32+slot)*128+j][3]: strip s slot sl: sl>s from col-dir of tile
// (sl,s); sl<s from row-dir of tile (s,sl); sl==s diagonal col-dir. Each written once.
__global__ __launch_bounds__(256) void corr_topk(const bf16* __restrict__ xnT,
                                                 const float* __restrict__ alpha_p,
                                                 const float* __restrict__ lsm,
                                                 float* __restrict__ wtop) {
    __shared__ __align__(16) bf16 SH[16384];  // 32KB
    bf16* As = SH;
    bf16* Bs = SH + 8192;
    int tid = threadIdx.x;
    int lin = blockIdx.x;
    int xcd = lin & 7;
    int b = xcd >> 1;
    int t = ((lin >> 3) << 1) + (xcd & 1);  // [0, 528)
    int mt, nt;
    decode_tri(t, mt, nt);
    int mbase = mt * 128, nbase = nt * 128;
    int wave = tid >> 6, lane = tid & 63;
    int wm = wave >> 1, wn = wave & 1, l15 = lane & 15, quad = lane >> 4;
    int rowi = (mbase + wm * 64) >> 6;
    int coli = (nbase + wn * 64) >> 6;
    int adr = rowi - coli; if (adr < 0) adr = -adr;
    float a2 = 2.0f * alpha_p[0];

    f32x4 acc[4][4];
    gemm_tile(xnT + ((size_t)b << 20), mbase, nbase, As, Bs, acc);

    // scratch: ext/mbuf in dead As-buf0 (bytes 0..5119, safe pre-barrier since
    // concurrent iter-7 readers touch only buf1); rtop used after __syncthreads.
    float* F = (float*)SH;
    float* ext  = F;              // [4][128]            floats 0..511
    float* mbuf = F + 512;        // [2][128][3]         floats 512..1279
    float* rtop = F + 1280;       // [128][48]: 16 slots x 3, stride 48 -> fits 32KB
    build_ext(ext + wave * 128, lane, adr, a2);
    float e[7][4];
    load_etab(ext + wave * 128, quad, l15, e);

    float lr[4][4];
#pragma unroll
    for (int mi = 0; mi < 4; ++mi)
#pragma unroll
        for (int r = 0; r < 4; ++r)
            lr[mi][r] = lsm[(b << 12) + mbase + wm * 64 + mi * 16 + quad * 4 + r];
    float lc[4];
#pragma unroll
    for (int ni = 0; ni < 4; ++ni)
        lc[ni] = lsm[(b << 12) + nbase + wn * 64 + ni * 16 + l15];

    // ---- column direction: top3 over rows for each tile column ----
#pragma unroll
    for (int ni = 0; ni < 4; ++ni) {
        float t0 = NEGINF, t1 = NEGINF, t2 = NEGINF;
#pragma unroll
        for (int mi = 0; mi < 4; ++mi) {
#pragma unroll
            for (int r = 0; r < 4; ++r) {
                float key = fmaf(e[mi - ni + 3][r], acc[mi][ni][r], lr[mi][r]);
                ins3(key, t0, t1, t2);
            }
        }
#pragma unroll
        for (int d = 16; d <= 32; d <<= 1) {
            float s0 = __shfl_xor(t0, d);
            float s1 = __shfl_xor(t1, d);
            float s2 = __shfl_xor(t2, d);
            ins3(s0, t0, t1, t2);
            ins3(s1, t0, t1, t2);
            ins3(s2, t0, t1, t2);
        }
        if (quad == 0) {
            int cl = wn * 64 + ni * 16 + l15;
            mbuf[(wm * 128 + cl) * 3 + 0] = t0;
            mbuf[(wm * 128 + cl) * 3 + 1] = t1;
            mbuf[(wm * 128 + cl) * 3 + 2] = t2;
        }
    }
    __syncthreads();  // all GEMM LDS reads done -> rtop region (overlaps bufs) reusable

    // ---- row direction (xc[c,n]=xc[n,c]): top3 over cols for each tile row ----
    if (mt != nt) {
#pragma unroll
        for (int mi = 0; mi < 4; ++mi) {
#pragma unroll
            for (int r = 0; r < 4; ++r) {
                float u0 = NEGINF, u1 = NEGINF, u2 = NEGINF;
#pragma unroll
                for (int ni = 0; ni < 4; ++ni) {
                    float key = fmaf(e[mi - ni + 3][r], acc[mi][ni][r], lc[ni]);
                    ins3(key, u0, u1, u2);
                }
                // one shuffle stage (xor 8): 16 -> 8 partials per row
                {
                    float s0 = __shfl_xor(u0, 8);
                    float s1 = __shfl_xor(u1, 8);
                    float s2 = __shfl_xor(u2, 8);
                    ins3(s0, u0, u1, u2);
                    ins3(s1, u0, u1, u2);
                    ins3(s2, u0, u1, u2);
                }
                if (l15 < 8) {
                    int row = wm * 64 + mi * 16 + quad * 4 + r;
                    int slot = wn * 8 + l15;
                    float* q = rtop + row * 48 + slot * 3;
                    q[0] = u0; q[1] = u1; q[2] = u2;
                }
            }
        }
    }
    __syncthreads();
    if (tid < 128) {
        // column-direction merge: strip nt, slot mt, column nbase+tid
        float t0 = mbuf[tid * 3], t1 = mbuf[tid * 3 + 1], t2 = mbuf[tid * 3 + 2];
        ins3(mbuf[(128 + tid) * 3 + 0], t0, t1, t2);
        ins3(mbuf[(128 + tid) * 3 + 1], t0, t1, t2);
        ins3(mbuf[(128 + tid) * 3 + 2], t0, t1, t2);
        size_t o = ((size_t)((b * 32 + nt) * 32 + mt) * 128 + tid) * 3;
        wtop[o] = t0;
        wtop[o + 1] = t1;
        wtop[o + 2] = t2;
        if (mt != nt) {
            // row-direction merge: strip mt, slot nt, column mbase+tid
            float v0 = NEGINF, v1 = NEGINF, v2 = NEGINF;
            const float* q = rtop + tid * 48;
#pragma unroll
            for (int sl = 0; sl < 16; ++sl) {
                ins3(q[sl * 3 + 0], v0, v1, v2);
                ins3(q[sl * 3 + 1], v0, v1, v2);
                ins3(q[sl * 3 + 2], v0, v1, v2);
            }
            size_t o2 = ((size_t)((b * 32 + mt) * 32 + nt) * 128 + tid) * 3;
            wtop[o2] = v0;
            wtop[o2 + 1] = v1;
            wtop[o2 + 2] = v2;
        }
    }
}

// ---------------- final merge of 32 slot-partials per column; exp + column scale ----------------
__global__ __launch_bounds__(256) void corr_merge(const float* __restrict__ wtop,
                                                  const float* __restrict__ ism,
                                                  float* __restrict__ out) {
    int idx = blockIdx.x * 256 + threadIdx.x;
    if (idx >= 4 * HW) return;
    int b = idx >> 12, col = idx & 4095;
    int strip = col >> 7, j = col & 127;
    const float* base = wtop + ((size_t)((b * 32 + strip) * 32) * 128 + j) * 3;
    float t0 = NEGINF, t1 = NEGINF, t2 = NEGINF;
    for (int sl = 0; sl < 32; ++sl) {
        const float* q = base + (size_t)sl * 128 * 3;
        ins3(q[0], t0, t1, t2);
        ins3(q[1], t0, t1, t2);
        ins3(q[2], t0, t1, t2);
    }
    float ismc = ism[idx];
    out[((b * 3 + 0) << 12) + col] = __expf(t0) * ismc;
    out[((b * 3 + 1) << 12) + col] = __expf(t1) * ismc;
    out[((b * 3 + 2) << 12) + col] = __expf(t2) * ismc;
}

extern "C" void kernel_launch(void* const* d_in, const int* in_sizes, int n_in,
                              void* d_out, int out_size, void* d_ws, size_t ws_size,
                              hipStream_t stream) {
    const float* x = (const float*)d_in[0];
    const float* alpha = (const float*)d_in[1];
    float* out = (float*)d_out;
    char* ws = (char*)d_ws;
    bf16* xnT = (bf16*)ws;                                    // 8 MB
    float* ism = (float*)(ws + (8u << 20));                   // 64 KB
    float* lsm = (float*)(ws + (8u << 20) + (64u << 10));     // 64 KB
    float* rpart = (float*)(ws + (8u << 20) + (128u << 10));  // 2 MB (rowsum->recip)
    float* wtop  = (float*)(ws + (8u << 20) + (128u << 10));  // 6 MB (topk->merge)

    corr_norm<<<256, 256, 0, stream>>>(x, xnT);
    corr_rowsum<<<528 * 4, 256, 0, stream>>>(xnT, alpha, rpart);
    corr_recip<<<64, 256, 0, stream>>>(rpart, ism, lsm);
    corr_topk<<<528 * 4, 256, 0, stream>>>(xnT, alpha, lsm, wtop);
    corr_merge<<<64, 256, 0, stream>>>(wtop, ism, out);
}

// Round 10
// 154.973 us; speedup vs baseline: 1.7698x; 1.0072x over previous
//
#include <hip/hip_runtime.h>
#include <hip/hip_bf16.h>

// Corr: B=4, C=256, H=W=64, HW=4096, TOPK=3, rat_s=0.05 -> sigma=3.2, 2*sigma^2=20.48
// s[m,n] = alpha * (1 - exp(-(dr^2+dc^2)/20.48)) * <xn_m, xn_n>  (symmetric)
// xc[m,n] = exp(2 s[m,n]) / (sm[m] sm[n]),  sm[m] = sum_n exp(s[m,n])
// out[b,k,col] = top-3 over m of xc[m,col]
//
// R1: XCD<->batch binding. R2: log-domain top-k. R3: non-atomic partials.
// R4: k-slot swizzle. R6: triangular dual-direction topk. R8: __syncthreads
// K-loop (raw vmcnt barriers w/ LDS-DMA are numerically unsafe -> banned).
// R9: (a) rtop stride 48->51 (48 mod 32 = 16 put the 16-slot tail merge on 2
//     banks -> 1.33M conflict cycles; 51 is odd -> all 32 banks); (b) corr_norm
//     LDS-transpose so xnT writes are lane-contiguous (old: 16B per lane at
//     512B stride = 4x write amplification on 8MB).

#define HW 4096
#define CDIM 256
#define INV2S2 0.048828125f  // 1/20.48
#define NEGINF -1e30f

typedef __bf16 bf16;
typedef __attribute__((ext_vector_type(8))) __bf16 bf16x8;
typedef __attribute__((ext_vector_type(4))) float f32x4;

#define GAS __attribute__((address_space(1)))
#define LAS __attribute__((address_space(3)))

__device__ __forceinline__ void ins3(float v, float& t0, float& t1, float& t2) {
    // maintains t0>=t1>=t2; exact top-3 insert in 3 VALU ops (v_max + 2x v_med3)
    float n0 = fmaxf(t0, v);
    float n1 = __builtin_amdgcn_fmed3f(t0, t1, v);
    float n2 = __builtin_amdgcn_fmed3f(t1, t2, v);
    t0 = n0; t1 = n1; t2 = n2;
}

// triangular decode: t = mt*(mt+1)/2 + nt, nt <= mt
__device__ __forceinline__ void decode_tri(int t, int& mt, int& nt) {
    int m = (int)((sqrtf(8.f * (float)t + 1.f) - 1.f) * 0.5f);
    while ((m + 1) * (m + 2) / 2 <= t) ++m;
    while (m * (m + 1) / 2 > t) --m;
    mt = m;
    nt = t - m * (m + 1) / 2;
}

// ---------------- normalize + transpose to bf16 xnT[b][pixel][channel] ----------------
// LDS-transposed store: global reads coalesced over pixels, global writes
// coalesced over channels (1KB contiguous per wave).
__global__ __launch_bounds__(256) void corr_norm(const float* __restrict__ x,
                                                 bf16* __restrict__ xnT) {
    __shared__ float red[4][64];
    __shared__ float invn[64];
    __shared__ __align__(16) bf16 T[64][264];  // 264 = 256 + 8 pad
    int tid = threadIdx.x;
    int pl = tid & 63, cg = tid >> 6;       // pixel-lane, channel-group
    int P0 = blockIdx.x * 64;
    int P = P0 + pl;
    int b = P >> 12;
    int pix = P & 4095;
    const float* xb = x + ((size_t)(b * CDIM + cg * 64) << 12) + pix;
    float v[64];
    float ss = 0.f;
#pragma unroll
    for (int j = 0; j < 64; ++j) {
        v[j] = xb[(size_t)j << 12];
        ss += v[j] * v[j];
    }
    red[cg][pl] = ss;
    __syncthreads();
    if (tid < 64) {
        float s = red[0][tid] + red[1][tid] + red[2][tid] + red[3][tid];
        invn[tid] = 1.0f / fmaxf(sqrtf(s), 1e-12f);
    }
    __syncthreads();
    float inv = invn[pl];
#pragma unroll
    for (int j0 = 0; j0 < 64; j0 += 8) {
        bf16x8 pk;
#pragma unroll
        for (int j = 0; j < 8; ++j) pk[j] = (bf16)(v[j0 + j] * inv);
        *(bf16x8*)(&T[pl][cg * 64 + j0]) = pk;
    }
    __syncthreads();
    // write out: lanes sweep channels -> contiguous 512B per pixel, 8 pixels/iter
#pragma unroll
    for (int it = 0; it < 8; ++it) {
        int p = it * 8 + (tid >> 5);
        int k = tid & 31;
        bf16x8 val = *(const bf16x8*)(&T[p][k * 8]);
        *(bf16x8*)(xnT + (size_t)(P0 + p) * CDIM + k * 8) = val;
    }
}

// ---------------- GEMM tile core: 128x128, K=256, dbuf single-barrier, k-slot swizzle ----
__device__ __forceinline__ void gemm_tile(const bf16* __restrict__ xb, int mbase, int nbase,
                                          bf16* As, bf16* Bs, f32x4 (&acc)[4][4]) {
    const int tid = threadIdx.x;
    const int wave = tid >> 6;
    const int lane = tid & 63;
    const int wm = wave >> 1, wn = wave & 1;
    const int l15 = lane & 15, quad = lane >> 4;
#pragma unroll
    for (int mi = 0; mi < 4; ++mi)
#pragma unroll
        for (int ni = 0; ni < 4; ++ni) acc[mi][ni] = (f32x4)0.f;

    auto issue = [&](int kk, int buf) {
#pragma unroll
        for (int r = 0; r < 2; ++r) {
            int idx = r * 256 + tid;
            int prow = idx >> 2;
            int sub = ((idx & 3) - (prow >> 1)) & 3;  // swizzled k-group
            const bf16* gA = xb + ((size_t)(mbase + prow) << 8) + kk * 32 + (sub << 3);
            const bf16* gB = xb + ((size_t)(nbase + prow) << 8) + kk * 32 + (sub << 3);
            bf16* lA = As + buf * 4096 + ((r * 4 + wave) << 9);
            bf16* lB = Bs + buf * 4096 + ((r * 4 + wave) << 9);
            __builtin_amdgcn_global_load_lds((const GAS void*)gA, (LAS void*)lA, 16, 0, 0);
            __builtin_amdgcn_global_load_lds((const GAS void*)gB, (LAS void*)lB, 16, 0, 0);
        }
    };
    issue(0, 0);
    const int rslot = ((quad + (l15 >> 1)) & 3) * 8;
#pragma unroll
    for (int kk = 0; kk < 8; ++kk) {
        __syncthreads();
        if (kk < 7) issue(kk + 1, (kk + 1) & 1);
        int buf = kk & 1;
        bf16x8 af[4], bfr[4];
#pragma unroll
        for (int i = 0; i < 4; ++i) {
            af[i]  = *(const bf16x8*)(As + buf * 4096 + (wm * 64 + i * 16 + l15) * 32 + rslot);
            bfr[i] = *(const bf16x8*)(Bs + buf * 4096 + (wn * 64 + i * 16 + l15) * 32 + rslot);
        }
#pragma unroll
        for (int mi = 0; mi < 4; ++mi)
#pragma unroll
            for (int ni = 0; ni < 4; ++ni)
                acc[mi][ni] = __builtin_amdgcn_mfma_f32_16x16x32_bf16(af[mi], bfr[ni],
                                                                      acc[mi][ni], 0, 0, 0);
    }
    // post-loop: all waves past the kk=7 barrier; iter-7 reads hit buf1 only,
    // so As/Bs buf0 regions are dead and reusable as epilogue scratch.
}

// extw[j] = scale*(1 - exp(-(adr^2+(j-63)^2)/20.48)), j in [0,128) — wave-private
__device__ __forceinline__ void build_ext(float* extw, int lane, int adr, float scale) {
    float fr2 = (float)(adr * adr);
#pragma unroll
    for (int h = 0; h < 2; ++h) {
        int j = lane + h * 64;
        float d = (float)(j - 63);
        extw[j] = scale * (1.f - __expf(-(fr2 + d * d) * INV2S2));
    }
}

// per-lane register table e[dm][r], dm = mi-ni+3
__device__ __forceinline__ void load_etab(const float* extw_wave, int quad, int l15,
                                          float (&e)[7][4]) {
    const float* p = extw_wave + 63 + quad * 4 - l15;
#pragma unroll
    for (int dm = 0; dm < 7; ++dm)
#pragma unroll
        for (int r = 0; r < 4; ++r) e[dm][r] = p[(dm - 3) * 16 + r];
}

// ---------------- pass B: rowsum partials, triangular tiles, no atomics ----------------
// rpart[((b*32 + strip)*32 + slot)*128 + j]: strip s gets row-sums from tiles (s, nt<=s)
// at slot nt, and col-sums from tiles (mt>s, s) at slot mt. Every slot written once.
__global__ __launch_bounds__(256) void corr_rowsum(const bf16* __restrict__ xnT,
                                                   const float* __restrict__ alpha_p,
                                                   float* __restrict__ rpart) {
    __shared__ __align__(16) bf16 SH[16384];  // 32KB: As[2][4096] | Bs[2][4096]
    bf16* As = SH;
    bf16* Bs = SH + 8192;
    int tid = threadIdx.x;
    int lin = blockIdx.x;
    int xcd = lin & 7;
    int b = xcd >> 1;
    int t = ((lin >> 3) << 1) + (xcd & 1);  // [0, 528)
    int mt, nt;
    decode_tri(t, mt, nt);
    int mbase = mt * 128, nbase = nt * 128;
    int wave = tid >> 6, lane = tid & 63;
    int wm = wave >> 1, wn = wave & 1, l15 = lane & 15, quad = lane >> 4;
    int rowi = (mbase + wm * 64) >> 6;
    int coli = (nbase + wn * 64) >> 6;
    int adr = rowi - coli; if (adr < 0) adr = -adr;
    float alpha = alpha_p[0];

    f32x4 acc[4][4];
    gemm_tile(xnT + ((size_t)b << 20), mbase, nbase, As, Bs, acc);

    // epilogue scratch in dead As-buf0 (bytes 0..4095)
    float* F = (float*)SH;
    float* ext  = F;              // [4][128] wave-private
    float* rbuf = F + 512;        // [2][128]
    float* cbuf = F + 768;        // [2][128]
    build_ext(ext + wave * 128, lane, adr, alpha);
    float e[7][4];
    load_etab(ext + wave * 128, quad, l15, e);

    float colpart[4] = {0.f, 0.f, 0.f, 0.f};
#pragma unroll
    for (int mi = 0; mi < 4; ++mi) {
#pragma unroll
        for (int r = 0; r < 4; ++r) {
            float ssum = 0.f;
#pragma unroll
            for (int ni = 0; ni < 4; ++ni) {
                float s = e[mi - ni + 3][r] * acc[mi][ni][r];
                float ev = __expf(s);
                ssum += ev;
                colpart[ni] += ev;
            }
            ssum += __shfl_xor(ssum, 1);
            ssum += __shfl_xor(ssum, 2);
            ssum += __shfl_xor(ssum, 4);
            ssum += __shfl_xor(ssum, 8);
            if (l15 == 0) rbuf[wn * 128 + wm * 64 + mi * 16 + quad * 4 + r] = ssum;
        }
    }
#pragma unroll
    for (int ni = 0; ni < 4; ++ni) {
        float c = colpart[ni];
        c += __shfl_xor(c, 16);
        c += __shfl_xor(c, 32);
        if (quad == 0) cbuf[wm * 128 + wn * 64 + ni * 16 + l15] = c;
    }
    __syncthreads();
    if (tid < 128) {
        rpart[(size_t)((b * 32 + mt) * 32 + nt) * 128 + tid] = rbuf[tid] + rbuf[128 + tid];
    } else if (mt != nt) {
        int j = tid - 128;
        rpart[(size_t)((b * 32 + nt) * 32 + mt) * 128 + j] = cbuf[j] + cbuf[128 + j];
    }
}

// ---------------- slot-reduce + reciprocal + negative log ----------------
__global__ __launch_bounds__(256) void corr_recip(const float* __restrict__ rpart,
                                                  float* __restrict__ ism,
                                                  float* __restrict__ lsm) {
    int i = blockIdx.x * 256 + threadIdx.x;
    if (i >= 4 * HW) return;
    int b = i >> 12, gr = i & 4095, s = gr >> 7, j = gr & 127;
    const float* base = rpart + (size_t)((b * 32 + s) * 32) * 128 + j;
    float sum = 0.f;
#pragma unroll
    for (int sl = 0; sl < 32; ++sl) sum += base[sl * 128];
    ism[i] = 1.0f / sum;
    lsm[i] = -__logf(sum);
}

// ---------------- pass C: triangular log-domain top-3, dual direction ----------------
// wtop[((b*32+strip)*32+slot)*128+j][3]: strip s slot sl: sl>s from col-dir of tile
// (sl,s); sl<s from row-dir of tile (s,sl); sl==s diagonal col-dir. Each written once.
__global__ __launch_bounds__(256) void corr_topk(const bf16* __restrict__ xnT,
                                                 const float* __restrict__ alpha_p,
                                                 const float* __restrict__ lsm,
                                                 float* __restrict__ wtop) {
    __shared__ __align__(16) bf16 SH[16384];  // 32KB
    bf16* As = SH;
    bf16* Bs = SH + 8192;
    int tid = threadIdx.x;
    int lin = blockIdx.x;
    int xcd = lin & 7;
    int b = xcd >> 1;
    int t = ((lin >> 3) << 1) + (xcd & 1);  // [0, 528)
    int mt, nt;
    decode_tri(t, mt, nt);
    int mbase = mt * 128, nbase = nt * 128;
    int wave = tid >> 6, lane = tid & 63;
    int wm = wave >> 1, wn = wave & 1, l15 = lane & 15, quad = lane >> 4;
    int rowi = (mbase + wm * 64) >> 6;
    int coli = (nbase + wn * 64) >> 6;
    int adr = rowi - coli; if (adr < 0) adr = -adr;
    float a2 = 2.0f * alpha_p[0];

    f32x4 acc[4][4];
    gemm_tile(xnT + ((size_t)b << 20), mbase, nbase, As, Bs, acc);

    // scratch: ext/mbuf in dead As-buf0; rtop (stride 51: odd -> full bank
    // spread; 1280+128*51=7808 floats = 31232B fits 32KB) used after barrier.
    float* F = (float*)SH;
    float* ext  = F;              // [4][128]            floats 0..511
    float* mbuf = F + 512;        // [2][128][3]         floats 512..1279
    float* rtop = F + 1280;       // [128][51]: 16 slots x 3 + pad
    build_ext(ext + wave * 128, lane, adr, a2);
    float e[7][4];
    load_etab(ext + wave * 128, quad, l15, e);

    float lr[4][4];
#pragma unroll
    for (int mi = 0; mi < 4; ++mi)
#pragma unroll
        for (int r = 0; r < 4; ++r)
            lr[mi][r] = lsm[(b << 12) + mbase + wm * 64 + mi * 16 + quad * 4 + r];
    float lc[4];
#pragma unroll
    for (int ni = 0; ni < 4; ++ni)
        lc[ni] = lsm[(b << 12) + nbase + wn * 64 + ni * 16 + l15];

    // ---- column direction: top3 over rows for each tile column ----
#pragma unroll
    for (int ni = 0; ni < 4; ++ni) {
        float t0 = NEGINF, t1 = NEGINF, t2 = NEGINF;
#pragma unroll
        for (int mi = 0; mi < 4; ++mi) {
#pragma unroll
            for (int r = 0; r < 4; ++r) {
                float key = fmaf(e[mi - ni + 3][r], acc[mi][ni][r], lr[mi][r]);
                ins3(key, t0, t1, t2);
            }
        }
#pragma unroll
        for (int d = 16; d <= 32; d <<= 1) {
            float s0 = __shfl_xor(t0, d);
            float s1 = __shfl_xor(t1, d);
            float s2 = __shfl_xor(t2, d);
            ins3(s0, t0, t1, t2);
            ins3(s1, t0, t1, t2);
            ins3(s2, t0, t1, t2);
        }
        if (quad == 0) {
            int cl = wn * 64 + ni * 16 + l15;
            mbuf[(wm * 128 + cl) * 3 + 0] = t0;
            mbuf[(wm * 128 + cl) * 3 + 1] = t1;
            mbuf[(wm * 128 + cl) * 3 + 2] = t2;
        }
    }
    __syncthreads();  // all GEMM LDS reads done -> rtop region (overlaps bufs) reusable

    // ---- row direction (xc[c,n]=xc[n,c]): top3 over cols for each tile row ----
    if (mt != nt) {
#pragma unroll
        for (int mi = 0; mi < 4; ++mi) {
#pragma unroll
            for (int r = 0; r < 4; ++r) {
                float u0 = NEGINF, u1 = NEGINF, u2 = NEGINF;
#pragma unroll
                for (int ni = 0; ni < 4; ++ni) {
                    float key = fmaf(e[mi - ni + 3][r], acc[mi][ni][r], lc[ni]);
                    ins3(key, u0, u1, u2);
                }
                // one shuffle stage (xor 8): 16 -> 8 partials per row
                {
                    float s0 = __shfl_xor(u0, 8);
                    float s1 = __shfl_xor(u1, 8);
                    float s2 = __shfl_xor(u2, 8);
                    ins3(s0, u0, u1, u2);
                    ins3(s1, u0, u1, u2);
                    ins3(s2, u0, u1, u2);
                }
                if (l15 < 8) {
                    int row = wm * 64 + mi * 16 + quad * 4 + r;
                    int slot = wn * 8 + l15;
                    float* q = rtop + row * 51 + slot * 3;
                    q[0] = u0; q[1] = u1; q[2] = u2;
                }
            }
        }
    }
    __syncthreads();
    if (tid < 128) {
        // column-direction merge: strip nt, slot mt, column nbase+tid
        float t0 = mbuf[tid * 3], t1 = mbuf[tid * 3 + 1], t2 = mbuf[tid * 3 + 2];
        ins3(mbuf[(128 + tid) * 3 + 0], t0, t1, t2);
        ins3(mbuf[(128 + tid) * 3 + 1], t0, t1, t2);
        ins3(mbuf[(128 + tid) * 3 + 2], t0, t1, t2);
        size_t o = ((size_t)((b * 32 + nt) * 32 + mt) * 128 + tid) * 3;
        wtop[o] = t0;
        wtop[o + 1] = t1;
        wtop[o + 2] = t2;
        if (mt != nt) {
            // row-direction merge: strip mt, slot nt, column mbase+tid
            float v0 = NEGINF, v1 = NEGINF, v2 = NEGINF;
            const float* q = rtop + tid * 51;
#pragma unroll
            for (int sl = 0; sl < 16; ++sl) {
                ins3(q[sl * 3 + 0], v0, v1, v2);
                ins3(q[sl * 3 + 1], v0, v1, v2);
                ins3(q[sl * 3 + 2], v0, v1, v2);
            }
            size_t o2 = ((size_t)((b * 32 + mt) * 32 + nt) * 128 + tid) * 3;
            wtop[o2] = v0;
            wtop[o2 + 1] = v1;
            wtop[o2 + 2] = v2;
        }
    }
}

// ---------------- final merge of 32 slot-partials per column; exp + column scale ----------------
__global__ __launch_bounds__(256) void corr_merge(const float* __restrict__ wtop,
                                                  const float* __restrict__ ism,
                                                  float* __restrict__ out) {
    int idx = blockIdx.x * 256 + threadIdx.x;
    if (idx >= 4 * HW) return;
    int b = idx >> 12, col = idx & 4095;
    int strip = col >> 7, j = col & 127;
    const float* base = wtop + ((size_t)((b * 32 + strip) * 32) * 128 + j) * 3;
    float t0 = NEGINF, t1 = NEGINF, t2 = NEGINF;
    for (int sl = 0; sl < 32; ++sl) {
        const float* q = base + (size_t)sl * 128 * 3;
        ins3(q[0], t0, t1, t2);
        ins3(q[1], t0, t1, t2);
        ins3(q[2], t0, t1, t2);
    }
    float ismc = ism[idx];
    out[((b * 3 + 0) << 12) + col] = __expf(t0) * ismc;
    out[((b * 3 + 1) << 12) + col] = __expf(t1) * ismc;
    out[((b * 3 + 2) << 12) + col] = __expf(t2) * ismc;
}

extern "C" void kernel_launch(void* const* d_in, const int* in_sizes, int n_in,
                              void* d_out, int out_size, void* d_ws, size_t ws_size,
                              hipStream_t stream) {
    const float* x = (const float*)d_in[0];
    const float* alpha = (const float*)d_in[1];
    float* out = (float*)d_out;
    char* ws = (char*)d_ws;
    bf16* xnT = (bf16*)ws;                                    // 8 MB
    float* ism = (float*)(ws + (8u << 20));                   // 64 KB
    float* lsm = (float*)(ws + (8u << 20) + (64u << 10));     // 64 KB
    float* rpart = (float*)(ws + (8u << 20) + (128u << 10));  // 2 MB (rowsum->recip)
    float* wtop  = (float*)(ws + (8u << 20) + (128u << 10));  // 6 MB (topk->merge)

    corr_norm<<<256, 256, 0, stream>>>(x, xnT);
    corr_rowsum<<<528 * 4, 256, 0, stream>>>(xnT, alpha, rpart);
    corr_recip<<<64, 256, 0, stream>>>(rpart, ism, lsm);
    corr_topk<<<528 * 4, 256, 0, stream>>>(xnT, alpha, lsm, wtop);
    corr_merge<<<64, 256, 0, stream>>>(wtop, ism, out);
}